// Round 2
// baseline (6978.024 us; speedup 1.0000x reference)
//
#include <hip/hip_runtime.h>
#include <stdint.h>
#include <stddef.h>

// ---------- types ----------
typedef __bf16 bf16_8 __attribute__((ext_vector_type(8)));
typedef float  f32x4  __attribute__((ext_vector_type(4)));

__device__ __forceinline__ unsigned short f2bf(float f) {
    unsigned u = __float_as_uint(f);
    unsigned r = (u + 0x7fffu + ((u >> 16) & 1u)) >> 16;   // RTN-even
    return (unsigned short)r;
}
__device__ __forceinline__ float bf2f(unsigned short s) {
    return __uint_as_float(((unsigned)s) << 16);
}

// ---------- GEMM: C[M,N] (+)= A[M,K](f32) * B[K,N](f32) via bf16 MFMA ----------
// 128x128 block tile, BK=32, 256 threads (2x2 waves, each wave 64x64 = 4x4 MFMA 16x16x32).
// TERMS=6: 3-term bf16 split of A and B (a=ah+al+al2 exact to 2^-27); keep all products
//          down to 2^-18 -> per-product error ~2^-26, i.e. fp32-grade (argmax-safe).
// TERMS=1: plain bf16 round of A and B (expert path, 2% tolerance).
template<int TERMS, bool ACCUM>
__global__ __launch_bounds__(256, 2)
void gemm_kernel(const float* __restrict__ A, const float* __restrict__ B,
                 float* __restrict__ C, int M, int N, int K)
{
    __shared__ unsigned short Ah[128 * 40];                      // 32 cols + 8 pad
    __shared__ unsigned short Bh[128 * 40];                      // transposed: Bh[n][k]
    __shared__ unsigned short Al [(TERMS == 6) ? 128 * 40 : 4];
    __shared__ unsigned short Al2[(TERMS == 6) ? 128 * 40 : 4];
    __shared__ unsigned short Bl [(TERMS == 6) ? 128 * 40 : 4];
    __shared__ unsigned short Bl2[(TERMS == 6) ? 128 * 40 : 4];

    const int tid   = threadIdx.x;
    const int lane  = tid & 63;
    const int wid   = tid >> 6;
    const int wm    = wid & 1, wn = wid >> 1;
    const int mlane = lane & 15, quad = lane >> 4;
    const int row0  = blockIdx.x * 128;
    const int col0  = blockIdx.y * 128;

    f32x4 acc[4][4];
#pragma unroll
    for (int i = 0; i < 4; ++i)
#pragma unroll
        for (int j = 0; j < 4; ++j)
#pragma unroll
            for (int r = 0; r < 4; ++r) acc[i][j][r] = 0.f;

    for (int k0 = 0; k0 < K; k0 += 32) {
        // ---- stage A: 128x32 f32, split to bf16 planes ----
#pragma unroll
        for (int i = 0; i < 4; ++i) {
            int idx = tid + (i << 8);            // 1024 float4 slots
            int r = idx >> 3;
            int c = (idx & 7) << 2;
            const float4 a = *(const float4*)(A + (size_t)(row0 + r) * K + k0 + c);
            float av[4] = {a.x, a.y, a.z, a.w};
            ushort4 hv, lv, l2v;
            unsigned short* hp  = (unsigned short*)&hv;
            unsigned short* lp  = (unsigned short*)&lv;
            unsigned short* l2p = (unsigned short*)&l2v;
#pragma unroll
            for (int j = 0; j < 4; ++j) {
                unsigned short h = f2bf(av[j]);
                hp[j] = h;
                if (TERMS == 6) {
                    float r1 = av[j] - bf2f(h);
                    unsigned short l = f2bf(r1);
                    lp[j]  = l;
                    l2p[j] = f2bf(r1 - bf2f(l));
                }
            }
            *(ushort4*)&Ah[r * 40 + c] = hv;
            if (TERMS == 6) {
                *(ushort4*)&Al [r * 40 + c] = lv;
                *(ushort4*)&Al2[r * 40 + c] = l2v;
            }
        }
        // ---- stage B: 32x128 f32 (coalesced), split + transpose to [n][k] ----
#pragma unroll
        for (int i = 0; i < 2; ++i) {
            int idx = tid + (i << 8);            // 512 chunks of 8 cols
            int kk = idx >> 4;
            int n8 = (idx & 15) << 3;
            const float* bp = B + (size_t)(k0 + kk) * N + col0 + n8;
            const float4 b0 = *(const float4*)bp;
            const float4 b1 = *(const float4*)(bp + 4);
            float bv[8] = {b0.x, b0.y, b0.z, b0.w, b1.x, b1.y, b1.z, b1.w};
#pragma unroll
            for (int j = 0; j < 8; ++j) {
                unsigned short h = f2bf(bv[j]);
                Bh[(n8 + j) * 40 + kk] = h;
                if (TERMS == 6) {
                    float r1 = bv[j] - bf2f(h);
                    unsigned short l = f2bf(r1);
                    Bl [(n8 + j) * 40 + kk] = l;
                    Bl2[(n8 + j) * 40 + kk] = f2bf(r1 - bf2f(l));
                }
            }
        }
        __syncthreads();

        // ---- fragments ----
        bf16_8 fa[3][4], fb[3][4];
#pragma unroll
        for (int t = 0; t < 4; ++t) {
            int ar = (wm * 64 + t * 16 + mlane) * 40 + quad * 8;
            int br = (wn * 64 + t * 16 + mlane) * 40 + quad * 8;
            fa[0][t] = *(const bf16_8*)&Ah[ar];
            fb[0][t] = *(const bf16_8*)&Bh[br];
            if (TERMS == 6) {
                fa[1][t] = *(const bf16_8*)&Al[ar];
                fa[2][t] = *(const bf16_8*)&Al2[ar];
                fb[1][t] = *(const bf16_8*)&Bl[br];
                fb[2][t] = *(const bf16_8*)&Bl2[br];
            }
        }
        // term s: A-plane ta[s] x B-plane tb[s]; magnitudes 1,2^-9,2^-9,2^-18,2^-18,2^-18
        const int ta[6] = {0, 0, 1, 0, 1, 2};
        const int tb[6] = {0, 1, 0, 2, 1, 0};
#pragma unroll
        for (int s = 0; s < TERMS; ++s)
#pragma unroll
            for (int mt = 0; mt < 4; ++mt)
#pragma unroll
                for (int nt = 0; nt < 4; ++nt)
                    acc[mt][nt] = __builtin_amdgcn_mfma_f32_16x16x32_bf16(
                        fa[ta[s]][mt], fb[tb[s]][nt], acc[mt][nt], 0, 0, 0);
        __syncthreads();
    }

    // ---- epilogue: C/D layout col=lane&15, row=quad*4+reg ----
#pragma unroll
    for (int mt = 0; mt < 4; ++mt)
#pragma unroll
        for (int nt = 0; nt < 4; ++nt) {
            int r = row0 + wm * 64 + mt * 16 + quad * 4;
            int c = col0 + wn * 64 + nt * 16 + mlane;
#pragma unroll
            for (int j = 0; j < 4; ++j) {
                float* p = C + (size_t)(r + j) * N + c;
                if (ACCUM) *p += acc[mt][nt][j];
                else       *p  = acc[mt][nt][j];
            }
        }
}

// ---------- fp32 flash attention over [B=8,S=1024,H=8,KH=64] flat [8192,512] ----------
__global__ __launch_bounds__(256, 2)
void attn_kernel(const float* __restrict__ Q, const float* __restrict__ Km,
                 const float* __restrict__ V, float* __restrict__ O)
{
    __shared__ float ks[64][68];
    __shared__ float vs[64][68];

    const int tid = threadIdx.x;
    const int qt  = blockIdx.x & 15;
    const int h   = (blockIdx.x >> 4) & 7;
    const int b   = blockIdx.x >> 7;
    const size_t rowbase = (size_t)b * 1024;
    const int colbase = h * 64;
    const int q = tid >> 2, sub = tid & 3;
    const size_t qrow = (rowbase + qt * 64 + q) * 512 + colbase;

    float qreg[64];
#pragma unroll
    for (int d = 0; d < 64; ++d) qreg[d] = Q[qrow + d];

    float oacc[64];
#pragma unroll
    for (int d = 0; d < 64; ++d) oacc[d] = 0.f;
    float m = -1e30f, l = 0.f;

    for (int tt = 0; tt < 16; ++tt) {
        __syncthreads();
#pragma unroll
        for (int i = 0; i < 4; ++i) {
            int idx = tid + (i << 8);
            int r = idx >> 4, c = (idx & 15) << 2;
            const size_t g = (rowbase + tt * 64 + r) * 512 + colbase + c;
            *(float4*)&ks[r][c] = *(const float4*)(Km + g);
            *(float4*)&vs[r][c] = *(const float4*)(V + g);
        }
        __syncthreads();

        float s[16];
#pragma unroll
        for (int jj = 0; jj < 16; ++jj) {
            int j = (jj << 2) + sub;
            float t = 0.f;
#pragma unroll
            for (int d = 0; d < 64; ++d) t += qreg[d] * ks[j][d];
            s[jj] = t * 0.125f;                  // 1/sqrt(64)
        }
        float mloc = s[0];
#pragma unroll
        for (int jj = 1; jj < 16; ++jj) mloc = fmaxf(mloc, s[jj]);
        float mnew = fmaxf(m, mloc);
        float alpha = __expf(m - mnew);
        float p[16]; float lt = 0.f;
#pragma unroll
        for (int jj = 0; jj < 16; ++jj) { p[jj] = __expf(s[jj] - mnew); lt += p[jj]; }
        l = l * alpha + lt;
#pragma unroll
        for (int d = 0; d < 64; ++d) oacc[d] *= alpha;
#pragma unroll
        for (int jj = 0; jj < 16; ++jj) {
            int j = (jj << 2) + sub;
#pragma unroll
            for (int d = 0; d < 64; ++d) oacc[d] += p[jj] * vs[j][d];
        }
        m = mnew;
    }

    // merge 4 partials (m,l,oacc) across sub lanes (4q..4q+3, same wave)
    float M2 = fmaxf(m, __shfl_xor(m, 1));
    M2 = fmaxf(M2, __shfl_xor(M2, 2));
    float w = __expf(m - M2);
    float lw = l * w;
    lw += __shfl_xor(lw, 1);
    lw += __shfl_xor(lw, 2);
    float inv = 1.f / lw;
#pragma unroll
    for (int d = 0; d < 64; ++d) {
        float od = oacc[d] * w;
        od += __shfl_xor(od, 1);
        od += __shfl_xor(od, 2);
        oacc[d] = od * inv;
    }
#pragma unroll
    for (int i = 0; i < 16; ++i)
        O[qrow + sub * 16 + i] = oacc[sub * 16 + i];
}

// ---------- embedding gather: X[t,:] = emb[tokens[t],:] (f32) ----------
__global__ void gather_kernel(const int* __restrict__ tokens,
                              const float* __restrict__ emb,
                              float* __restrict__ X)
{
    const int t = blockIdx.x;
    const int tok = tokens[t];
    const float4* src = (const float4*)(emb + (size_t)tok * 512);
    float4* dst = (float4*)(X + (size_t)t * 512);
    for (int d = threadIdx.x; d < 128; d += 128) dst[d] = src[d];
}

// ---------- gate + argmax (fp32, first-max tiebreak like np.argmax) ----------
__global__ __launch_bounds__(256)
void gate_kernel(const float* __restrict__ H, const float* __restrict__ Wg,
                 int* __restrict__ idx)
{
    const int t = blockIdx.x * 4 + (threadIdx.x >> 6);
    const int lane = threadIdx.x & 63;
    float a0 = 0, a1 = 0, a2 = 0, a3 = 0;
#pragma unroll
    for (int i = 0; i < 8; ++i) {
        int d = i * 64 + lane;
        float hv = H[(size_t)t * 512 + d];
        a0 += hv * Wg[d * 4 + 0];
        a1 += hv * Wg[d * 4 + 1];
        a2 += hv * Wg[d * 4 + 2];
        a3 += hv * Wg[d * 4 + 3];
    }
#pragma unroll
    for (int off = 32; off > 0; off >>= 1) {
        a0 += __shfl_down(a0, off);
        a1 += __shfl_down(a1, off);
        a2 += __shfl_down(a2, off);
        a3 += __shfl_down(a3, off);
    }
    if (lane == 0) {
        int best = 0; float bv = a0;
        if (a1 > bv) { bv = a1; best = 1; }
        if (a2 > bv) { bv = a2; best = 2; }
        if (a3 > bv) { bv = a3; best = 3; }
        idx[t] = best;
    }
}

// ---------- expert mask: Xe = (idx==e) ? H : 0 ----------
__global__ void mask_kernel(const float* __restrict__ H, const int* __restrict__ idx,
                            float* __restrict__ Xe, int e)
{
    const int i = blockIdx.x * 256 + threadIdx.x;   // over 8192*128 float4
    const int t = i >> 7;
    float4 z; z.x = z.y = z.z = z.w = 0.f;
    float4 v = (idx[t] == e) ? ((const float4*)H)[i] : z;
    ((float4*)Xe)[i] = v;
}

// ---------- head: out[t] = OUT[t,:] . Wout (f32 out) ----------
__global__ __launch_bounds__(256)
void wout_kernel(const float* __restrict__ OUT, const float* __restrict__ Wout,
                 float* __restrict__ out)
{
    const int t = blockIdx.x * 4 + (threadIdx.x >> 6);
    const int lane = threadIdx.x & 63;
    float s = 0.f;
#pragma unroll
    for (int i = 0; i < 8; ++i) {
        int d = i * 64 + lane;
        s += OUT[(size_t)t * 512 + d] * Wout[d];
    }
#pragma unroll
    for (int off = 32; off > 0; off >>= 1) s += __shfl_down(s, off);
    if (lane == 0) out[t] = s;
}

// ---------- launch ----------
extern "C" void kernel_launch(void* const* d_in, const int* in_sizes, int n_in,
                              void* d_out, int out_size, void* d_ws, size_t ws_size,
                              hipStream_t stream)
{
    const int*   tokens = (const int*)d_in[0];
    const float* emb  = (const float*)d_in[1];
    const float* Wq   = (const float*)d_in[2];
    const float* Wk   = (const float*)d_in[3];
    const float* Wv   = (const float*)d_in[4];
    const float* Wo   = (const float*)d_in[5];
    const float* W1   = (const float*)d_in[6];
    const float* W2   = (const float*)d_in[7];
    const float* Wg   = (const float*)d_in[8];
    const float* eWq  = (const float*)d_in[9];
    const float* eWk  = (const float*)d_in[10];
    const float* eWv  = (const float*)d_in[11];
    const float* eWo  = (const float*)d_in[12];
    const float* eW1  = (const float*)d_in[13];
    const float* eW2  = (const float*)d_in[14];
    const float* Wout = (const float*)d_in[15];
    float* outp = (float*)d_out;

    float* WS = (float*)d_ws;
    const size_t SZ = (size_t)8192 * 512;    // one [8192,512] fp32 plane
    float* X  = WS;              // also T0 / Xe (X dead after QKV)
    float* Qb = WS + SZ;
    float* Kb = WS + 2 * SZ;
    float* Vb = WS + 3 * SZ;
    float* AO = WS + 4 * SZ;
    float* T1 = Qb;              // [8192,2048] aliases Qb..AO (dead during FFN)
    float* T0 = X;
    float* Hb = WS + 5 * SZ;
    float* OA = WS + 6 * SZ;
    int*  IDX = (int*)(WS + 7 * SZ);

    const int M = 8192, D = 512, FF = 2048;
    dim3 gD(M / 128, D / 128), gF(M / 128, FF / 128);

    // shared block: 6-term split GEMMs (argmax upstream must match np fp32 ref)
    gather_kernel<<<8192, 128, 0, stream>>>(tokens, emb, X);
    gemm_kernel<6, false><<<gD, 256, 0, stream>>>(X,  Wq, Qb, M, D, D);
    gemm_kernel<6, false><<<gD, 256, 0, stream>>>(X,  Wk, Kb, M, D, D);
    gemm_kernel<6, false><<<gD, 256, 0, stream>>>(X,  Wv, Vb, M, D, D);
    attn_kernel<<<1024, 256, 0, stream>>>(Qb, Kb, Vb, AO);
    gemm_kernel<6, false><<<gD, 256, 0, stream>>>(AO, Wo, T0, M, D, D);
    gemm_kernel<6, false><<<gF, 256, 0, stream>>>(T0, W1, T1, M, FF, D);
    gemm_kernel<6, false><<<gD, 256, 0, stream>>>(T1, W2, Hb, M, D, FF);

    gate_kernel<<<2048, 256, 0, stream>>>(Hb, Wg, IDX);
    hipMemsetAsync(OA, 0, SZ * sizeof(float), stream);

    // expert blocks: plain bf16 GEMMs (2% tolerance downstream of argmax)
    for (int e = 0; e < 4; ++e) {
        mask_kernel<<<(8192 * 128) / 256, 256, 0, stream>>>(Hb, IDX, X, e);
        gemm_kernel<1, false><<<gD, 256, 0, stream>>>(X,  eWq + (size_t)e * D * D,  Qb, M, D, D);
        gemm_kernel<1, false><<<gD, 256, 0, stream>>>(X,  eWk + (size_t)e * D * D,  Kb, M, D, D);
        gemm_kernel<1, false><<<gD, 256, 0, stream>>>(X,  eWv + (size_t)e * D * D,  Vb, M, D, D);
        attn_kernel<<<1024, 256, 0, stream>>>(Qb, Kb, Vb, AO);
        gemm_kernel<1, false><<<gD, 256, 0, stream>>>(AO, eWo + (size_t)e * D * D,  T0, M, D, D);
        gemm_kernel<1, false><<<gF, 256, 0, stream>>>(T0, eW1 + (size_t)e * D * FF, T1, M, FF, D);
        gemm_kernel<1, true ><<<gD, 256, 0, stream>>>(T1, eW2 + (size_t)e * FF * D, OA, M, D, FF);
    }
    wout_kernel<<<2048, 256, 0, stream>>>(OA, Wout, outp);
}

// Round 3
// 5314.231 us; speedup vs baseline: 1.3131x; 1.3131x over previous
//
#include <hip/hip_runtime.h>
#include <stdint.h>
#include <stddef.h>

// ---------- types ----------
typedef __bf16 bf16_8 __attribute__((ext_vector_type(8)));
typedef float  f32x4  __attribute__((ext_vector_type(4)));

__device__ __forceinline__ unsigned short f2bf(float f) {
    unsigned u = __float_as_uint(f);
    unsigned r = (u + 0x7fffu + ((u >> 16) & 1u)) >> 16;   // RTN-even
    return (unsigned short)r;
}
__device__ __forceinline__ float bf2f(unsigned short s) {
    return __uint_as_float(((unsigned)s) << 16);
}

// ---------- GEMM: C[M,N] (+)= A[M,K](f32) * B[K,N](f32) via bf16 MFMA ----------
// 128x128 block tile, BK=32, 256 threads (2x2 waves, each wave 64x64 = 4x4 MFMA 16x16x32).
// TERMS=6: 3-term bf16 split of A and B (fp32-grade, argmax-safe).
// TERMS=1: plain bf16 round (expert path, 2% tolerance).
template<int TERMS, bool ACCUM>
__global__ __launch_bounds__(256, 2)
void gemm_kernel(const float* __restrict__ A, const float* __restrict__ B,
                 float* __restrict__ C, int M, int N, int K)
{
    __shared__ unsigned short Ah[128 * 40];                      // 32 cols + 8 pad
    __shared__ unsigned short Bh[128 * 40];                      // transposed: Bh[n][k]
    __shared__ unsigned short Al [(TERMS == 6) ? 128 * 40 : 4];
    __shared__ unsigned short Al2[(TERMS == 6) ? 128 * 40 : 4];
    __shared__ unsigned short Bl [(TERMS == 6) ? 128 * 40 : 4];
    __shared__ unsigned short Bl2[(TERMS == 6) ? 128 * 40 : 4];

    const int tid   = threadIdx.x;
    const int lane  = tid & 63;
    const int wid   = tid >> 6;
    const int wm    = wid & 1, wn = wid >> 1;
    const int mlane = lane & 15, quad = lane >> 4;
    const int row0  = blockIdx.x * 128;
    const int col0  = blockIdx.y * 128;

    f32x4 acc[4][4];
#pragma unroll
    for (int i = 0; i < 4; ++i)
#pragma unroll
        for (int j = 0; j < 4; ++j)
#pragma unroll
            for (int r = 0; r < 4; ++r) acc[i][j][r] = 0.f;

    for (int k0 = 0; k0 < K; k0 += 32) {
        // ---- stage A: 128x32 f32, split to bf16 planes ----
#pragma unroll
        for (int i = 0; i < 4; ++i) {
            int idx = tid + (i << 8);            // 1024 float4 slots
            int r = idx >> 3;
            int c = (idx & 7) << 2;
            const float4 a = *(const float4*)(A + (size_t)(row0 + r) * K + k0 + c);
            float av[4] = {a.x, a.y, a.z, a.w};
            ushort4 hv, lv, l2v;
            unsigned short* hp  = (unsigned short*)&hv;
            unsigned short* lp  = (unsigned short*)&lv;
            unsigned short* l2p = (unsigned short*)&l2v;
#pragma unroll
            for (int j = 0; j < 4; ++j) {
                unsigned short h = f2bf(av[j]);
                hp[j] = h;
                if (TERMS == 6) {
                    float r1 = av[j] - bf2f(h);
                    unsigned short l = f2bf(r1);
                    lp[j]  = l;
                    l2p[j] = f2bf(r1 - bf2f(l));
                }
            }
            *(ushort4*)&Ah[r * 40 + c] = hv;
            if (TERMS == 6) {
                *(ushort4*)&Al [r * 40 + c] = lv;
                *(ushort4*)&Al2[r * 40 + c] = l2v;
            }
        }
        // ---- stage B: 32x128 f32 (coalesced), split + transpose to [n][k] ----
#pragma unroll
        for (int i = 0; i < 2; ++i) {
            int idx = tid + (i << 8);            // 512 chunks of 8 cols
            int kk = idx >> 4;
            int n8 = (idx & 15) << 3;
            const float* bp = B + (size_t)(k0 + kk) * N + col0 + n8;
            const float4 b0 = *(const float4*)bp;
            const float4 b1 = *(const float4*)(bp + 4);
            float bv[8] = {b0.x, b0.y, b0.z, b0.w, b1.x, b1.y, b1.z, b1.w};
#pragma unroll
            for (int j = 0; j < 8; ++j) {
                unsigned short h = f2bf(bv[j]);
                Bh[(n8 + j) * 40 + kk] = h;
                if (TERMS == 6) {
                    float r1 = bv[j] - bf2f(h);
                    unsigned short l = f2bf(r1);
                    Bl [(n8 + j) * 40 + kk] = l;
                    Bl2[(n8 + j) * 40 + kk] = f2bf(r1 - bf2f(l));
                }
            }
        }
        __syncthreads();

        // ---- fragments ----
        bf16_8 fa[3][4], fb[3][4];
#pragma unroll
        for (int t = 0; t < 4; ++t) {
            int ar = (wm * 64 + t * 16 + mlane) * 40 + quad * 8;
            int br = (wn * 64 + t * 16 + mlane) * 40 + quad * 8;
            fa[0][t] = *(const bf16_8*)&Ah[ar];
            fb[0][t] = *(const bf16_8*)&Bh[br];
            if (TERMS == 6) {
                fa[1][t] = *(const bf16_8*)&Al[ar];
                fa[2][t] = *(const bf16_8*)&Al2[ar];
                fb[1][t] = *(const bf16_8*)&Bl[br];
                fb[2][t] = *(const bf16_8*)&Bl2[br];
            }
        }
        // term s: A-plane ta[s] x B-plane tb[s]
        const int ta[6] = {0, 0, 1, 0, 1, 2};
        const int tb[6] = {0, 1, 0, 2, 1, 0};
#pragma unroll
        for (int s = 0; s < TERMS; ++s)
#pragma unroll
            for (int mt = 0; mt < 4; ++mt)
#pragma unroll
                for (int nt = 0; nt < 4; ++nt)
                    acc[mt][nt] = __builtin_amdgcn_mfma_f32_16x16x32_bf16(
                        fa[ta[s]][mt], fb[tb[s]][nt], acc[mt][nt], 0, 0, 0);
        __syncthreads();
    }

    // ---- epilogue: C/D layout col=lane&15, row=quad*4+reg ----
#pragma unroll
    for (int mt = 0; mt < 4; ++mt)
#pragma unroll
        for (int nt = 0; nt < 4; ++nt) {
            int r = row0 + wm * 64 + mt * 16 + quad * 4;
            int c = col0 + wn * 64 + nt * 16 + mlane;
#pragma unroll
            for (int j = 0; j < 4; ++j) {
                float* p = C + (size_t)(r + j) * N + c;
                if (ACCUM) *p += acc[mt][nt][j];
                else       *p  = acc[mt][nt][j];
            }
        }
}

// ---------- fp32 flash attention, d-sliced (no spills) ----------
// [B=8,S=1024,H=8,KH=64] flat [8192,512]. Block = (b,h,64-query tile), 256 threads:
// 4 threads per query, thread (q,sub) owns d-slice [sub*16, sub*16+16) of q and O.
// Scores: partial dot over own 16 dims, shfl_xor butterfly -> bit-identical full score
// in all 4 subs -> all subs track identical (m,l); no final merge needed.
__global__ __launch_bounds__(256, 4)
void attn_kernel(const float* __restrict__ Q, const float* __restrict__ Km,
                 const float* __restrict__ V, float* __restrict__ O)
{
    __shared__ float ks[64][68];
    __shared__ float vs[64][68];

    const int tid = threadIdx.x;
    const int qt  = blockIdx.x & 15;
    const int h   = (blockIdx.x >> 4) & 7;
    const int b   = blockIdx.x >> 7;
    const size_t rowbase = (size_t)b * 1024;
    const int colbase = h * 64;
    const int q = tid >> 2, sub = tid & 3;
    const int ds = sub << 4;                         // own d-slice start
    const size_t qrow = (rowbase + qt * 64 + q) * 512 + colbase;

    float4 qreg[4];
#pragma unroll
    for (int i = 0; i < 4; ++i) qreg[i] = *(const float4*)(Q + qrow + ds + i * 4);

    float4 oacc[4];
#pragma unroll
    for (int i = 0; i < 4; ++i) { oacc[i].x = oacc[i].y = oacc[i].z = oacc[i].w = 0.f; }
    float m = -1e30f, l = 0.f;

    for (int tt = 0; tt < 16; ++tt) {
        __syncthreads();
#pragma unroll
        for (int i = 0; i < 4; ++i) {
            int idx = tid + (i << 8);
            int r = idx >> 4, c = (idx & 15) << 2;
            const size_t g = (rowbase + tt * 64 + r) * 512 + colbase + c;
            *(float4*)&ks[r][c] = *(const float4*)(Km + g);
            *(float4*)&vs[r][c] = *(const float4*)(V + g);
        }
        __syncthreads();

#pragma unroll
        for (int c = 0; c < 4; ++c) {                // 4 chunks of 16 j
            float s[16];
#pragma unroll
            for (int jj = 0; jj < 16; ++jj) {
                const int j = (c << 4) + jj;
                const float* kp = &ks[j][ds];
                float4 k0 = *(const float4*)kp;
                float4 k1 = *(const float4*)(kp + 4);
                float4 k2 = *(const float4*)(kp + 8);
                float4 k3 = *(const float4*)(kp + 12);
                float t = qreg[0].x * k0.x + qreg[0].y * k0.y + qreg[0].z * k0.z + qreg[0].w * k0.w
                        + qreg[1].x * k1.x + qreg[1].y * k1.y + qreg[1].z * k1.z + qreg[1].w * k1.w
                        + qreg[2].x * k2.x + qreg[2].y * k2.y + qreg[2].z * k2.z + qreg[2].w * k2.w
                        + qreg[3].x * k3.x + qreg[3].y * k3.y + qreg[3].z * k3.z + qreg[3].w * k3.w;
                t += __shfl_xor(t, 1);               // butterfly: full dot, bit-identical
                t += __shfl_xor(t, 2);               // across the 4 subs of this query
                s[jj] = t * 0.125f;                  // 1/sqrt(64)
            }
            float mloc = s[0];
#pragma unroll
            for (int jj = 1; jj < 16; ++jj) mloc = fmaxf(mloc, s[jj]);
            float mnew = fmaxf(m, mloc);
            float alpha = __expf(m - mnew);
            float lt = 0.f;
#pragma unroll
            for (int jj = 0; jj < 16; ++jj) { s[jj] = __expf(s[jj] - mnew); lt += s[jj]; }
            l = l * alpha + lt;
#pragma unroll
            for (int i = 0; i < 4; ++i) {
                oacc[i].x *= alpha; oacc[i].y *= alpha;
                oacc[i].z *= alpha; oacc[i].w *= alpha;
            }
#pragma unroll
            for (int jj = 0; jj < 16; ++jj) {
                const float pj = s[jj];
                const float* vp = &vs[(c << 4) + jj][ds];
#pragma unroll
                for (int i = 0; i < 4; ++i) {
                    float4 v = *(const float4*)(vp + i * 4);
                    oacc[i].x += pj * v.x; oacc[i].y += pj * v.y;
                    oacc[i].z += pj * v.z; oacc[i].w += pj * v.w;
                }
            }
            m = mnew;
        }
    }

    const float inv = 1.f / l;
#pragma unroll
    for (int i = 0; i < 4; ++i) {
        float4 o;
        o.x = oacc[i].x * inv; o.y = oacc[i].y * inv;
        o.z = oacc[i].z * inv; o.w = oacc[i].w * inv;
        *(float4*)(O + qrow + ds + i * 4) = o;
    }
}

// ---------- embedding gather: X[t,:] = emb[tokens[t],:] (f32) ----------
__global__ void gather_kernel(const int* __restrict__ tokens,
                              const float* __restrict__ emb,
                              float* __restrict__ X)
{
    const int t = blockIdx.x;
    const int tok = tokens[t];
    const float4* src = (const float4*)(emb + (size_t)tok * 512);
    float4* dst = (float4*)(X + (size_t)t * 512);
    for (int d = threadIdx.x; d < 128; d += 128) dst[d] = src[d];
}

// ---------- gate + argmax (fp32, first-max tiebreak like np.argmax) ----------
__global__ __launch_bounds__(256)
void gate_kernel(const float* __restrict__ H, const float* __restrict__ Wg,
                 int* __restrict__ idx)
{
    const int t = blockIdx.x * 4 + (threadIdx.x >> 6);
    const int lane = threadIdx.x & 63;
    float a0 = 0, a1 = 0, a2 = 0, a3 = 0;
#pragma unroll
    for (int i = 0; i < 8; ++i) {
        int d = i * 64 + lane;
        float hv = H[(size_t)t * 512 + d];
        a0 += hv * Wg[d * 4 + 0];
        a1 += hv * Wg[d * 4 + 1];
        a2 += hv * Wg[d * 4 + 2];
        a3 += hv * Wg[d * 4 + 3];
    }
#pragma unroll
    for (int off = 32; off > 0; off >>= 1) {
        a0 += __shfl_down(a0, off);
        a1 += __shfl_down(a1, off);
        a2 += __shfl_down(a2, off);
        a3 += __shfl_down(a3, off);
    }
    if (lane == 0) {
        int best = 0; float bv = a0;
        if (a1 > bv) { bv = a1; best = 1; }
        if (a2 > bv) { bv = a2; best = 2; }
        if (a3 > bv) { bv = a3; best = 3; }
        idx[t] = best;
    }
}

// ---------- expert mask: Xe = (idx==e) ? H : 0 ----------
__global__ void mask_kernel(const float* __restrict__ H, const int* __restrict__ idx,
                            float* __restrict__ Xe, int e)
{
    const int i = blockIdx.x * 256 + threadIdx.x;   // over 8192*128 float4
    const int t = i >> 7;
    float4 z; z.x = z.y = z.z = z.w = 0.f;
    float4 v = (idx[t] == e) ? ((const float4*)H)[i] : z;
    ((float4*)Xe)[i] = v;
}

// ---------- head: out[t] = OUT[t,:] . Wout (f32 out) ----------
__global__ __launch_bounds__(256)
void wout_kernel(const float* __restrict__ OUT, const float* __restrict__ Wout,
                 float* __restrict__ out)
{
    const int t = blockIdx.x * 4 + (threadIdx.x >> 6);
    const int lane = threadIdx.x & 63;
    float s = 0.f;
#pragma unroll
    for (int i = 0; i < 8; ++i) {
        int d = i * 64 + lane;
        s += OUT[(size_t)t * 512 + d] * Wout[d];
    }
#pragma unroll
    for (int off = 32; off > 0; off >>= 1) s += __shfl_down(s, off);
    if (lane == 0) out[t] = s;
}

// ---------- launch ----------
extern "C" void kernel_launch(void* const* d_in, const int* in_sizes, int n_in,
                              void* d_out, int out_size, void* d_ws, size_t ws_size,
                              hipStream_t stream)
{
    const int*   tokens = (const int*)d_in[0];
    const float* emb  = (const float*)d_in[1];
    const float* Wq   = (const float*)d_in[2];
    const float* Wk   = (const float*)d_in[3];
    const float* Wv   = (const float*)d_in[4];
    const float* Wo   = (const float*)d_in[5];
    const float* W1   = (const float*)d_in[6];
    const float* W2   = (const float*)d_in[7];
    const float* Wg   = (const float*)d_in[8];
    const float* eWq  = (const float*)d_in[9];
    const float* eWk  = (const float*)d_in[10];
    const float* eWv  = (const float*)d_in[11];
    const float* eWo  = (const float*)d_in[12];
    const float* eW1  = (const float*)d_in[13];
    const float* eW2  = (const float*)d_in[14];
    const float* Wout = (const float*)d_in[15];
    float* outp = (float*)d_out;

    float* WS = (float*)d_ws;
    const size_t SZ = (size_t)8192 * 512;    // one [8192,512] fp32 plane
    float* X  = WS;              // also T0 / Xe (X dead after QKV)
    float* Qb = WS + SZ;
    float* Kb = WS + 2 * SZ;
    float* Vb = WS + 3 * SZ;
    float* AO = WS + 4 * SZ;
    float* T1 = Qb;              // [8192,2048] aliases Qb..AO (dead during FFN)
    float* T0 = X;
    float* Hb = WS + 5 * SZ;
    float* OA = WS + 6 * SZ;
    int*  IDX = (int*)(WS + 7 * SZ);

    const int M = 8192, D = 512, FF = 2048;
    dim3 gD(M / 128, D / 128), gF(M / 128, FF / 128);

    // shared block: 6-term split GEMMs (argmax upstream must match np fp32 ref)
    gather_kernel<<<8192, 128, 0, stream>>>(tokens, emb, X);
    gemm_kernel<6, false><<<gD, 256, 0, stream>>>(X,  Wq, Qb, M, D, D);
    gemm_kernel<6, false><<<gD, 256, 0, stream>>>(X,  Wk, Kb, M, D, D);
    gemm_kernel<6, false><<<gD, 256, 0, stream>>>(X,  Wv, Vb, M, D, D);
    attn_kernel<<<1024, 256, 0, stream>>>(Qb, Kb, Vb, AO);
    gemm_kernel<6, false><<<gD, 256, 0, stream>>>(AO, Wo, T0, M, D, D);
    gemm_kernel<6, false><<<gF, 256, 0, stream>>>(T0, W1, T1, M, FF, D);
    gemm_kernel<6, false><<<gD, 256, 0, stream>>>(T1, W2, Hb, M, D, FF);

    gate_kernel<<<2048, 256, 0, stream>>>(Hb, Wg, IDX);
    hipMemsetAsync(OA, 0, SZ * sizeof(float), stream);

    // expert blocks: plain bf16 GEMMs (2% tolerance downstream of argmax)
    for (int e = 0; e < 4; ++e) {
        mask_kernel<<<(8192 * 128) / 256, 256, 0, stream>>>(Hb, IDX, X, e);
        gemm_kernel<1, false><<<gD, 256, 0, stream>>>(X,  eWq + (size_t)e * D * D,  Qb, M, D, D);
        gemm_kernel<1, false><<<gD, 256, 0, stream>>>(X,  eWk + (size_t)e * D * D,  Kb, M, D, D);
        gemm_kernel<1, false><<<gD, 256, 0, stream>>>(X,  eWv + (size_t)e * D * D,  Vb, M, D, D);
        attn_kernel<<<1024, 256, 0, stream>>>(Qb, Kb, Vb, AO);
        gemm_kernel<1, false><<<gD, 256, 0, stream>>>(AO, eWo + (size_t)e * D * D,  T0, M, D, D);
        gemm_kernel<1, false><<<gF, 256, 0, stream>>>(T0, eW1 + (size_t)e * D * FF, T1, M, FF, D);
        gemm_kernel<1, true ><<<gD, 256, 0, stream>>>(T1, eW2 + (size_t)e * FF * D, OA, M, D, FF);
    }
    wout_kernel<<<2048, 256, 0, stream>>>(OA, Wout, outp);
}